// Round 4
// baseline (676.858 us; speedup 1.0000x reference)
//
#include <hip/hip_runtime.h>
#include <hip/hip_bf16.h>

__device__ __forceinline__ float rt_bf(float x) { return __bfloat162float(__float2bfloat16(x)); }

// Direct circular convolution: out[b,h,n] = sum_m bf16(u[b,h,m]) * k[h,(n-m)&1023]
// One block per (b,h) pair. Thread t owns outputs n = 4t..4t+3 (shift-register
// reuse: one new LDS k-read per m). k is duplicated (2048) and +1-per-32 padded
// so the stride-4 lane pattern is <=2-way bank aliased (free on CDNA4).
__global__ __launch_bounds__(256)
void conv_direct(const float* __restrict__ U, const float* __restrict__ K,
                 float* __restrict__ OUT)
{
    __shared__ float su[1024];    // bf16-rounded u row
    __shared__ float skp[2112];   // k row duplicated + padded

    const int t  = threadIdx.x;
    const int h  = blockIdx.x & 1023;
    const int bb = blockIdx.x >> 10;
    const size_t ub = ((size_t)bb * 1024 + h) * 1024;
    const size_t kb = (size_t)h * 1024;

    #pragma unroll
    for (int rep = 0; rep < 4; ++rep) {
        int i = t + rep * 256;
        su[i] = rt_bf(U[ub + i]);
    }
    #pragma unroll
    for (int rep = 0; rep < 8; ++rep) {
        int i = t + rep * 256;
        float v = K[kb + (i & 1023)];
        skp[i + (i >> 5)] = v;    // sk[i] = k[i mod 1024], padded address
    }
    __syncthreads();

    // window registers: kw[j] = k[(4t + j - m) & 1023] = sk[4t + j - m + 1024]
    float o0 = 0.f, o1 = 0.f, o2 = 0.f, o3 = 0.f;
    int aw = 4 * t + 1024;                      // sk index of kw0 at m=0
    float kw0 = skp[aw     + ((aw    ) >> 5)];
    float kw1 = skp[aw + 1 + ((aw + 1) >> 5)];
    float kw2 = skp[aw + 2 + ((aw + 2) >> 5)];
    float kw3 = skp[aw + 3 + ((aw + 3) >> 5)];

    #pragma unroll 8
    for (int m = 0; m < 1024; ++m) {
        float um = su[m];                       // wave-broadcast (same addr)
        o0 = fmaf(um, kw0, o0);
        o1 = fmaf(um, kw1, o1);
        o2 = fmaf(um, kw2, o2);
        o3 = fmaf(um, kw3, o3);
        --aw;                                   // slide window down by 1
        kw3 = kw2; kw2 = kw1; kw1 = kw0;
        kw0 = skp[aw + (aw >> 5)];              // min aw = 4t >= 0, max 2047
    }

    *reinterpret_cast<float4*>(OUT + ub + 4 * t) = make_float4(o0, o1, o2, o3);
}

extern "C" void kernel_launch(void* const* d_in, const int* in_sizes, int n_in,
                              void* d_out, int out_size, void* d_ws, size_t ws_size,
                              hipStream_t stream) {
    // size-based identification of u and k; thresholds chosen to be correct
    // whether in_sizes holds element counts (16777216 / 1048576) or bytes
    // (67108864 / 4194304).
    int iu = -1, ik = -1;
    for (int i = 0; i < n_in; ++i) {
        if      (in_sizes[i] >= 8000000) iu = i;
        else if (in_sizes[i] >=  262144) ik = i;
    }
    if (iu < 0) iu = 0;
    if (ik < 0) ik = 1;

    const float* U = (const float*)d_in[iu];
    const float* K = (const float*)d_in[ik];
    float* OUT = (float*)d_out;

    conv_direct<<<dim3(16 * 1024), dim3(256), 0, stream>>>(U, K, OUT);
}